// Round 1
// baseline (854.419 us; speedup 1.0000x reference)
//
#include <hip/hip_runtime.h>
#include <cstdint>
#include <cstddef>
#include <cmath>

#define F_IN 256
#define HDIM 128
#define CCLS 40

// ---------------- row L2 norm: one wave per row ----------------
__global__ __launch_bounds__(256) void norm_kernel(const float* __restrict__ x,
                                                   float* __restrict__ inv_norm, int n) {
  int wv = threadIdx.x >> 6, l = threadIdx.x & 63;
  int row = blockIdx.x * 4 + wv;
  if (row >= n) return;
  float4 v = *(const float4*)(x + (size_t)row * F_IN + l * 4);
  float s = v.x * v.x + v.y * v.y + v.z * v.z + v.w * v.w;
#pragma unroll
  for (int off = 32; off; off >>= 1) s += __shfl_xor(s, off, 64);
  if (l == 0) inv_norm[row] = 1.0f / fmaxf(sqrtf(s), 1e-12f);
}

// ---------------- CSR build ----------------
__global__ __launch_bounds__(256) void hist_kernel(const int* __restrict__ dst,
                                                   int* __restrict__ counts, int e) {
  int i = blockIdx.x * 256 + threadIdx.x;
  if (i < e) atomicAdd(&counts[dst[i]], 1);
}

__global__ __launch_bounds__(1024) void scan_kernel(const int* __restrict__ counts,
                                                    int* __restrict__ row_off,
                                                    int* __restrict__ cursor, int n) {
  __shared__ int sums[1024];
  int t = threadIdx.x;
  int chunk = (n + 1023) >> 10;
  int beg = t * chunk, end = min(beg + chunk, n);
  int s = 0;
  for (int j = beg; j < end; ++j) s += counts[j];
  sums[t] = s;
  __syncthreads();
  for (int off = 1; off < 1024; off <<= 1) {
    int v = sums[t];
    if (t >= off) v += sums[t - off];
    __syncthreads();
    sums[t] = v;
    __syncthreads();
  }
  int run = (t == 0) ? 0 : sums[t - 1];
  for (int j = beg; j < end; ++j) {
    row_off[j] = run;
    cursor[j] = run;
    run += counts[j];
  }
  if (t == 1023) row_off[n] = sums[1023];
}

__global__ __launch_bounds__(256) void scatter_kernel(const int* __restrict__ src,
                                                      const int* __restrict__ dst,
                                                      const float* __restrict__ w,
                                                      int* __restrict__ cursor,
                                                      uint2* __restrict__ ews, int e) {
  int i = blockIdx.x * 256 + threadIdx.x;
  if (i < e) {
    int d = dst[i];
    int pos = atomicAdd(&cursor[d], 1);
    ews[pos] = make_uint2((unsigned)src[i], __float_as_uint(w[i]));
  }
}

// ---------------- fp32 tiled GEMM: C[M][128] = (scale.A)[M][K] @ W[K][128] ----------------
template <int K, bool SCALE>
__global__ __launch_bounds__(256) void gemm_kernel(const float* __restrict__ A,
                                                   const float* __restrict__ W,
                                                   const float* __restrict__ scale,
                                                   float* __restrict__ C, int M) {
  __shared__ float As[64][33];
  __shared__ float Bs[32][128];
  const int t = threadIdx.x;
  const int tx = t & 15, ty = t >> 4;  // tx: 16 col-groups of 8, ty: 16 row-groups of 4
  const int m0 = blockIdx.x * 64;
  float acc[4][8];
#pragma unroll
  for (int r = 0; r < 4; ++r)
#pragma unroll
    for (int c = 0; c < 8; ++c) acc[r][c] = 0.f;

  for (int k0 = 0; k0 < K; k0 += 32) {
#pragma unroll
    for (int j = 0; j < 2; ++j) {  // stage A: 64 rows x 32 k
      int i = t + j * 256;
      int row = i >> 3, q = i & 7;
      int gr = m0 + row;
      float4 v = make_float4(0.f, 0.f, 0.f, 0.f);
      if (gr < M) {
        v = *(const float4*)(A + (size_t)gr * K + k0 + q * 4);
        if (SCALE) {
          float sc = scale[gr];
          v.x *= sc; v.y *= sc; v.z *= sc; v.w *= sc;
        }
      }
      As[row][q * 4 + 0] = v.x;
      As[row][q * 4 + 1] = v.y;
      As[row][q * 4 + 2] = v.z;
      As[row][q * 4 + 3] = v.w;
    }
#pragma unroll
    for (int j = 0; j < 4; ++j) {  // stage B: 32 k x 128 n
      int i = t + j * 256;
      int kr = i >> 5, n4 = i & 31;
      *(float4*)&Bs[kr][n4 * 4] = *(const float4*)(W + (size_t)(k0 + kr) * HDIM + n4 * 4);
    }
    __syncthreads();
#pragma unroll
    for (int kr = 0; kr < 32; ++kr) {
      float a[4];
#pragma unroll
      for (int r = 0; r < 4; ++r) a[r] = As[ty * 4 + r][kr];
      float4 b0 = *(const float4*)&Bs[kr][tx * 8];
      float4 b1 = *(const float4*)&Bs[kr][tx * 8 + 4];
      float bb[8] = {b0.x, b0.y, b0.z, b0.w, b1.x, b1.y, b1.z, b1.w};
#pragma unroll
      for (int r = 0; r < 4; ++r)
#pragma unroll
        for (int c = 0; c < 8; ++c) acc[r][c] += a[r] * bb[c];
    }
    __syncthreads();
  }
#pragma unroll
  for (int r = 0; r < 4; ++r) {
    int gr = m0 + ty * 4 + r;
    if (gr < M) {
      float4 o0 = make_float4(acc[r][0], acc[r][1], acc[r][2], acc[r][3]);
      float4 o1 = make_float4(acc[r][4], acc[r][5], acc[r][6], acc[r][7]);
      *(float4*)(C + (size_t)gr * HDIM + tx * 8) = o0;
      *(float4*)(C + (size_t)gr * HDIM + tx * 8 + 4) = o1;
    }
  }
}

// ---------------- SPMM (CSR by dst): out[i] = sum w * x[src], +bias, opt relu ----------------
__global__ __launch_bounds__(256) void spmm_kernel(const float* __restrict__ xin,
                                                   const uint2* __restrict__ ews,
                                                   const int* __restrict__ row_off,
                                                   const float* __restrict__ bias,
                                                   float* __restrict__ outp, int n,
                                                   int do_relu) {
  int f = threadIdx.x & 127;
  int node = blockIdx.x * 2 + (threadIdx.x >> 7);
  if (node >= n) return;
  int e0 = row_off[node], e1 = row_off[node + 1];
  float acc = 0.f;
  int e = e0;
  for (; e + 4 <= e1; e += 4) {
    uint2 p0 = ews[e], p1 = ews[e + 1], p2 = ews[e + 2], p3 = ews[e + 3];
    acc += __uint_as_float(p0.y) * xin[(size_t)p0.x * HDIM + f];
    acc += __uint_as_float(p1.y) * xin[(size_t)p1.x * HDIM + f];
    acc += __uint_as_float(p2.y) * xin[(size_t)p2.x * HDIM + f];
    acc += __uint_as_float(p3.y) * xin[(size_t)p3.x * HDIM + f];
  }
  for (; e < e1; ++e) {
    uint2 p = ews[e];
    acc += __uint_as_float(p.y) * xin[(size_t)p.x * HDIM + f];
  }
  acc += bias[f];
  if (do_relu) acc = fmaxf(acc, 0.f);
  outp[(size_t)node * HDIM + f] = acc;
}

// ---------------- fold label-emb weights: Wc = We @ Wf_top, bc = be @ Wf_top + bf ----------------
__global__ __launch_bounds__(256) void wc_kernel(const float* __restrict__ We,
                                                 const float* __restrict__ be,
                                                 const float* __restrict__ Wf,
                                                 const float* __restrict__ bf,
                                                 float* __restrict__ Wc,
                                                 float* __restrict__ bc) {
  int t = threadIdx.x;
  for (int i = t; i < CCLS * CCLS; i += 256) {
    int c = i / CCLS, j = i % CCLS;
    float s = 0.f;
    for (int f = 0; f < HDIM; ++f) s += We[c * HDIM + f] * Wf[f * CCLS + j];
    Wc[i] = s;
  }
  if (t < CCLS) {
    float s = bf[t];
    for (int f = 0; f < HDIM; ++f) s += be[f] * Wf[f * CCLS + t];
    bc[t] = s;
  }
}

// ---------------- head: logits = y@Wc + h2@Wf_bot + bc, softmax ----------------
__global__ __launch_bounds__(256) void head_kernel(const float* __restrict__ y,
                                                   const float* __restrict__ h2,
                                                   const float* __restrict__ Wc,
                                                   const float* __restrict__ bc,
                                                   const float* __restrict__ Wf,
                                                   float* __restrict__ out, int n) {
  __shared__ float sW[168][44];   // rows 0..39: Wc, rows 40..167: Wf[128:256]
  __shared__ float zb[4][172];    // per-wave z = [y(40) | h2(128)]
  const int t = threadIdx.x;
  for (int i = t; i < CCLS * CCLS; i += 256) sW[i / CCLS][i % CCLS] = Wc[i];
  for (int i = t; i < HDIM * CCLS; i += 256) sW[CCLS + i / CCLS][i % CCLS] = Wf[HDIM * CCLS + i];
  __syncthreads();
  const int wv = t >> 6, l = t & 63;
  float bcl = (l < CCLS) ? bc[l] : 0.f;
  float* z = zb[wv];
  for (int it = 0; it < 16; ++it) {
    int node = blockIdx.x * 64 + wv * 16 + it;
    int nc = node < n ? node : n - 1;
    if (l < CCLS) z[l] = y[(size_t)nc * CCLS + l];
    z[40 + l] = h2[(size_t)nc * HDIM + l];
    z[104 + l] = h2[(size_t)nc * HDIM + 64 + l];
    __syncthreads();
    float acc = (l < CCLS) ? bcl : -INFINITY;
#pragma unroll
    for (int k = 0; k < 168; k += 4) {
      float4 zv = *(const float4*)&z[k];
      if (l < CCLS) {
        acc += zv.x * sW[k + 0][l];
        acc += zv.y * sW[k + 1][l];
        acc += zv.z * sW[k + 2][l];
        acc += zv.w * sW[k + 3][l];
      }
    }
    float m = acc;
#pragma unroll
    for (int off = 32; off; off >>= 1) m = fmaxf(m, __shfl_xor(m, off, 64));
    float ev = (l < CCLS) ? __expf(acc - m) : 0.f;
    float sum = ev;
#pragma unroll
    for (int off = 32; off; off >>= 1) sum += __shfl_xor(sum, off, 64);
    if (node < n && l < CCLS) out[(size_t)node * CCLS + l] = ev / sum;
    __syncthreads();  // protect z against next iteration's writes
  }
}

extern "C" void kernel_launch(void* const* d_in, const int* in_sizes, int n_in,
                              void* d_out, int out_size, void* d_ws, size_t ws_size,
                              hipStream_t stream) {
  (void)n_in; (void)out_size; (void)ws_size;
  const float* features = (const float*)d_in[0];
  const int*   src      = (const int*)d_in[1];
  const int*   dst      = (const int*)d_in[2];
  const float* ew       = (const float*)d_in[3];
  const float* y        = (const float*)d_in[4];
  const float* W1       = (const float*)d_in[5];
  const float* b1       = (const float*)d_in[6];
  const float* W2       = (const float*)d_in[7];
  const float* b2       = (const float*)d_in[8];
  const float* We       = (const float*)d_in[9];
  const float* be       = (const float*)d_in[10];
  const float* Wf       = (const float*)d_in[11];
  const float* bf       = (const float*)d_in[12];
  float* out = (float*)d_out;

  const int n = in_sizes[0] / F_IN;   // 50000
  const int e = in_sizes[1];          // 1600000

  char* w = (char*)d_ws;
  auto take = [&](size_t bytes) {
    char* p = w;
    w += (bytes + 255) & ~(size_t)255;
    return p;
  };
  float* inv_norm = (float*)take((size_t)n * 4);
  int*   counts   = (int*)take((size_t)n * 4);
  int*   row_off  = (int*)take((size_t)(n + 1) * 4);
  int*   cursor   = (int*)take((size_t)n * 4);
  uint2* ews      = (uint2*)take((size_t)e * 8);
  float* bufA     = (float*)take((size_t)n * HDIM * 4);
  float* bufB     = (float*)take((size_t)n * HDIM * 4);
  float* Wc       = (float*)take(CCLS * CCLS * 4);
  float* bc       = (float*)take(CCLS * 4);

  hipMemsetAsync(counts, 0, (size_t)n * 4, stream);
  norm_kernel<<<(n + 3) / 4, 256, 0, stream>>>(features, inv_norm, n);
  hist_kernel<<<(e + 255) / 256, 256, 0, stream>>>(dst, counts, e);
  scan_kernel<<<1, 1024, 0, stream>>>(counts, row_off, cursor, n);
  scatter_kernel<<<(e + 255) / 256, 256, 0, stream>>>(src, dst, ew, cursor, ews, e);
  wc_kernel<<<1, 256, 0, stream>>>(We, be, Wf, bf, Wc, bc);

  gemm_kernel<F_IN, true><<<(n + 63) / 64, 256, 0, stream>>>(features, W1, inv_norm, bufA, n);
  spmm_kernel<<<(n + 1) / 2, 256, 0, stream>>>(bufA, ews, row_off, b1, bufB, n, 1);
  gemm_kernel<HDIM, false><<<(n + 63) / 64, 256, 0, stream>>>(bufB, W2, nullptr, bufA, n);
  spmm_kernel<<<(n + 1) / 2, 256, 0, stream>>>(bufA, ews, row_off, b2, bufB, n, 0);
  head_kernel<<<(n + 63) / 64, 256, 0, stream>>>(y, bufB, Wc, bc, Wf, out, n);
}